// Round 6
// baseline (2601.627 us; speedup 1.0000x reference)
//
#include <hip/hip_runtime.h>
#include <hip/hip_bf16.h>
#include <hip/hip_fp16.h>
#include <stdint.h>

#define NNODES 50000
#define NPAD   50048          // 391 * 128 (= 782 * 64)
#define DEG    16
#define DIN    963
#define K0PAD  992            // 31 * 32
#define DHID   256
#define SCALE  (1.0f / 1024.0f)
#define ISCALE 1024.0f

typedef __attribute__((ext_vector_type(4))) float    f32x4;
typedef __attribute__((ext_vector_type(8))) _Float16 f16x8;
typedef __attribute__((ext_vector_type(4))) _Float16 f16x4;

typedef const __attribute__((address_space(1))) void GV;
typedef __attribute__((address_space(3))) void LV;

__device__ __forceinline__ void gl2lds16(const void* g, void* l) {
    __builtin_amdgcn_global_load_lds((GV*)g, (LV*)l, 16, 0, 0);
}

// ---------------- layer-0 dual GEMM (round-2 proven, ~140us) ----------------
// A: [NPAD][K0PAD] fp16. Wp: [512][K0PAD] fp16 (Wp[n][k]=W[k][n]; 0..255 self, 256..511 neigh).
// Grid (NPAD/128, 4), 256 thr = 4 waves, block tile 128x128, wave tile 64x64.
__global__ __launch_bounds__(256) void gemm_dual0(
    const _Float16* __restrict__ A, int K,
    const _Float16* __restrict__ Wp,
    _Float16* __restrict__ ys, _Float16* __restrict__ yn)
{
    __shared__ _Float16 lds[2][2][4096];   // [buf][A/B][kh(4)][128][8]

    const int tid  = threadIdx.x;
    const int w    = tid >> 6;
    const int lane = tid & 63;
    const int bm   = blockIdx.x * 128;
    const int nb   = blockIdx.y * 128;

    const int KT = K >> 5;

    auto stage = [&](int s, int kt) {
        const int k0 = kt << 5;
#pragma unroll
        for (int i = 0; i < 2; ++i) {
            const int j   = w + (i << 2);
            const int c   = (j << 6) + lane;
            const int row = c & 127;
            const int k8  = (c >> 7) << 3;
            gl2lds16(A  + (size_t)(bm + row) * K + k0 + k8, &lds[s][0][(size_t)j << 9]);
            gl2lds16(Wp + (size_t)(nb + row) * K + k0 + k8, &lds[s][1][(size_t)j << 9]);
        }
    };

    const int wm = (w >> 1) << 6;
    const int wn = (w & 1) << 6;
    const int lr = lane & 15;
    const int kh = lane >> 4;

    f32x4 acc[4][4] = {};

    stage(0, 0);
    __syncthreads();
    int cur = 0;
    for (int kt = 0; kt < KT; ++kt) {
        if (kt + 1 < KT) stage(cur ^ 1, kt + 1);
        f16x8 a[4], b[4];
#pragma unroll
        for (int mi = 0; mi < 4; ++mi)
            a[mi] = *(const f16x8*)&lds[cur][0][((kh << 7) + wm + (mi << 4) + lr) << 3];
#pragma unroll
        for (int ni = 0; ni < 4; ++ni)
            b[ni] = *(const f16x8*)&lds[cur][1][((kh << 7) + wn + (ni << 4) + lr) << 3];
#pragma unroll
        for (int mi = 0; mi < 4; ++mi)
#pragma unroll
            for (int ni = 0; ni < 4; ++ni)
                acc[mi][ni] = __builtin_amdgcn_mfma_f32_16x16x32_f16(a[mi], b[ni], acc[mi][ni], 0, 0, 0);
        __syncthreads();
        cur ^= 1;
    }

    _Float16* C = (blockIdx.y < 2) ? ys : yn;
    const int cb = (nb & 255) + wn;
#pragma unroll
    for (int mi = 0; mi < 4; ++mi) {
        const size_t rbase = (size_t)(bm + wm + (mi << 4) + (kh << 2)) << 8;
#pragma unroll
        for (int ni = 0; ni < 4; ++ni) {
            const int col = cb + (ni << 4) + lr;
#pragma unroll
            for (int r = 0; r < 4; ++r)
                C[rbase + ((size_t)r << 8) + col] = (_Float16)acc[mi][ni][r];
        }
    }
}

// ---------------- fused hidden layer v2: out = epi([X | gather(X)] @ Wcat + b) --------------
// Tile 64(M) x 256(N), 256 thr = 4 waves, each wave 64x64 (full M), acc[4][4].
// Steps 0..7 (self half): A and B fragments loaded DIRECTLY global->reg (L1/L2-hot),
// no LDS, no barriers. Steps 8..15 (neigh half): aggregate slice (64 rows x 32 k)
// built in registers (16-nbr fp16 tree sum) and routed through an 8KB double-buffered
// LDS; gather loads for step kt+1 issue before MFMA(kt); one barrier/step with vmcnt
// naturally drained (no stall).
template<int FINAL>
__global__ __launch_bounds__(256) void fused_layer(
    const _Float16* __restrict__ X, const int* __restrict__ nbr,
    const _Float16* __restrict__ W, const float* __restrict__ bias,
    const _Float16* __restrict__ res,
    _Float16* __restrict__ outh, float* __restrict__ outf)
{
    __shared__ _Float16 ldsG[2][2048];   // [kq(4)][64][8] per buffer

    const int tid  = threadIdx.x;
    const int w    = tid >> 6;
    const int lane = tid & 63;

    // bijective XCD swizzle (m204)
    const int nwg = gridDim.x, bid = blockIdx.x;
    const int q = nwg >> 3, r_ = nwg & 7, xc = bid & 7;
    const int wgid = (xc < r_ ? xc * (q + 1) : r_ * (q + 1) + (xc - r_) * q) + (bid >> 3);
    const int bm = wgid << 6;

    // gather role: row = lane, k-quarter = wave
    const int growg = bm + lane;
    const int nrow  = (growg < NNODES) ? growg : (NNODES - 1);
    const int4* np  = (const int4*)(nbr + nrow * DEG);
    const int4 q0 = np[0], q1 = np[1], q2 = np[2], q3 = np[3];
    const int kqo = w << 3;

    const int wn = w << 6;
    const int lr = lane & 15;
    const int kh = lane >> 4;

    f32x4 acc[4][4] = {};

    auto GLD = [&](int r, int ko) -> f16x8 {
        return *(const f16x8*)(X + ((size_t)r << 8) + ko);
    };

    // pre-gather for step 8 (neigh k-window 0), first 8 neighbours
    f16x8 g0 = GLD(q0.x, kqo), g1 = GLD(q0.y, kqo), g2 = GLD(q0.z, kqo), g3 = GLD(q0.w, kqo);
    f16x8 g4 = GLD(q1.x, kqo), g5 = GLD(q1.y, kqo), g6 = GLD(q1.z, kqo), g7 = GLD(q1.w, kqo);

    // ---- self region: steps 0..7, no LDS, no barriers ----
#pragma unroll
    for (int kt = 0; kt < 8; ++kt) {
        f16x8 a[4], b[4];
#pragma unroll
        for (int mi = 0; mi < 4; ++mi)
            a[mi] = *(const f16x8*)(X + ((size_t)(bm + (mi << 4) + lr) << 8) + (kt << 5) + (kh << 3));
#pragma unroll
        for (int ni = 0; ni < 4; ++ni)
            b[ni] = *(const f16x8*)(W + ((size_t)(wn + (ni << 4) + lr) << 9) + (kt << 5) + (kh << 3));
#pragma unroll
        for (int mi = 0; mi < 4; ++mi)
#pragma unroll
            for (int ni = 0; ni < 4; ++ni)
                acc[mi][ni] = __builtin_amdgcn_mfma_f32_16x16x32_f16(a[mi], b[ni], acc[mi][ni], 0, 0, 0);
    }

    // finish pre-gather for step 8
    {
        f16x8 s0 = ((g0 + g1) + (g2 + g3)) + ((g4 + g5) + (g6 + g7));
        g0 = GLD(q2.x, kqo); g1 = GLD(q2.y, kqo); g2 = GLD(q2.z, kqo); g3 = GLD(q2.w, kqo);
        g4 = GLD(q3.x, kqo); g5 = GLD(q3.y, kqo); g6 = GLD(q3.z, kqo); g7 = GLD(q3.w, kqo);
        f16x8 s1 = ((g0 + g1) + (g2 + g3)) + ((g4 + g5) + (g6 + g7));
        *(f16x8*)&ldsG[0][(w << 9) + (lane << 3)] = s0 + s1;
    }
    __syncthreads();

    // ---- gather region: steps 8..15 ----
#pragma unroll
    for (int kt = 8; kt < 16; ++kt) {
        const int cb = kt & 1;
        const int ko = ((kt - 7) << 5) + kqo;   // X k-window for step kt+1
        f16x8 h0, h1, h2, h3, h4, h5, h6, h7;
        if (kt < 15) {   // issue first 8 gather loads for step kt+1 (latency under MFMA)
            h0 = GLD(q0.x, ko); h1 = GLD(q0.y, ko); h2 = GLD(q0.z, ko); h3 = GLD(q0.w, ko);
            h4 = GLD(q1.x, ko); h5 = GLD(q1.y, ko); h6 = GLD(q1.z, ko); h7 = GLD(q1.w, ko);
        }
        f16x8 a[4], b[4];
#pragma unroll
        for (int ni = 0; ni < 4; ++ni)
            b[ni] = *(const f16x8*)(W + ((size_t)(wn + (ni << 4) + lr) << 9) + (kt << 5) + (kh << 3));
#pragma unroll
        for (int mi = 0; mi < 4; ++mi)
            a[mi] = *(const f16x8*)&ldsG[cb][(kh << 9) + (((mi << 4) + lr) << 3)];
#pragma unroll
        for (int mi = 0; mi < 4; ++mi)
#pragma unroll
            for (int ni = 0; ni < 4; ++ni)
                acc[mi][ni] = __builtin_amdgcn_mfma_f32_16x16x32_f16(a[mi], b[ni], acc[mi][ni], 0, 0, 0);
        if (kt < 15) {
            f16x8 s0 = ((h0 + h1) + (h2 + h3)) + ((h4 + h5) + (h6 + h7));
            h0 = GLD(q2.x, ko); h1 = GLD(q2.y, ko); h2 = GLD(q2.z, ko); h3 = GLD(q2.w, ko);
            h4 = GLD(q3.x, ko); h5 = GLD(q3.y, ko); h6 = GLD(q3.z, ko); h7 = GLD(q3.w, ko);
            f16x8 s1 = ((h0 + h1) + (h2 + h3)) + ((h4 + h5) + (h6 + h7));
            *(f16x8*)&ldsG[cb ^ 1][(w << 9) + (lane << 3)] = s0 + s1;
        }
        __syncthreads();
    }

    // epilogue. C/D: col = lane&15, row-in-tile = (lane>>4)*4 + r  [m89/m91]
    const int r0 = kh << 2;
#pragma unroll
    for (int mi = 0; mi < 4; ++mi) {
        const int grow0 = bm + (mi << 4) + r0;
#pragma unroll
        for (int ni = 0; ni < 4; ++ni) {
            const int col = wn + (ni << 4) + lr;
            const float bcol = bias[col] * SCALE;
#pragma unroll
            for (int r = 0; r < 4; ++r) {
                const int grow = grow0 + r;
                float s = acc[mi][ni][r] + bcol;
                s = fmaxf(s, 0.f);
                if (res) s = ((float)res[((size_t)grow << 8) + col] + s) * 0.5f;
                if (FINAL) {
                    if (grow < NNODES) outf[((size_t)grow << 8) + col] = s * ISCALE;
                } else {
                    outh[((size_t)grow << 8) + col] = (_Float16)s;
                }
            }
        }
    }
}

// ------------- layer-0 combine: P = relu(ys + sum_j yn[nbr_j] + b0*SCALE) -------------
__global__ __launch_bounds__(256) void combine0(
    const _Float16* __restrict__ ys, const _Float16* __restrict__ yn,
    const int* __restrict__ nbr, const float* __restrict__ bias,
    _Float16* __restrict__ outh)
{
    const int w    = threadIdx.x >> 6;
    const int lane = threadIdx.x & 63;
    const int n    = (blockIdx.x << 2) + w;
    const int c4   = lane << 2;
    const size_t base = ((size_t)n << 8) + c4;

    const f16x4 ysv = *(const f16x4*)(ys + base);
    const float4 bv = *(const float4*)(bias + c4);
    float s0 = (float)ysv[0] + bv.x * SCALE;
    float s1 = (float)ysv[1] + bv.y * SCALE;
    float s2 = (float)ysv[2] + bv.z * SCALE;
    float s3 = (float)ysv[3] + bv.w * SCALE;

    const int* nr = nbr + n * DEG;
#pragma unroll
    for (int j = 0; j < DEG; ++j) {
        const f16x4 v = *(const f16x4*)(yn + (((size_t)nr[j]) << 8) + c4);
        s0 += (float)v[0]; s1 += (float)v[1]; s2 += (float)v[2]; s3 += (float)v[3];
    }
    f16x4 o;
    o[0] = (_Float16)fmaxf(s0, 0.f); o[1] = (_Float16)fmaxf(s1, 0.f);
    o[2] = (_Float16)fmaxf(s2, 0.f); o[3] = (_Float16)fmaxf(s3, 0.f);
    *(f16x4*)(outh + base) = o;
}

// ------------- coords head: out3 = x @ We (256x3) + be (fp32, unscaled) -------------
__global__ __launch_bounds__(64) void coords_kernel(
    const float* __restrict__ x, const float* __restrict__ We,
    const float* __restrict__ be, float* __restrict__ out3, int N)
{
    const int n = blockIdx.x;
    const int l = threadIdx.x;
    const float4 xv = *(const float4*)(x + (size_t)n * 256 + l * 4);
    float p0 = 0.f, p1 = 0.f, p2 = 0.f;
    const float xs[4] = {xv.x, xv.y, xv.z, xv.w};
#pragma unroll
    for (int i = 0; i < 4; ++i) {
        const int cidx = l * 4 + i;
        p0 += xs[i] * We[cidx * 3 + 0];
        p1 += xs[i] * We[cidx * 3 + 1];
        p2 += xs[i] * We[cidx * 3 + 2];
    }
#pragma unroll
    for (int off = 32; off > 0; off >>= 1) {
        p0 += __shfl_down(p0, off);
        p1 += __shfl_down(p1, off);
        p2 += __shfl_down(p2, off);
    }
    if (l == 0) {
        out3[(size_t)n * 3 + 0] = p0 + be[0];
        out3[(size_t)n * 3 + 1] = p1 + be[1];
        out3[(size_t)n * 3 + 2] = p2 + be[2];
    }
}

// ------------- conversion / packing kernels -------------
__global__ __launch_bounds__(256) void conv_sf(const float* __restrict__ sf,
                                               _Float16* __restrict__ sfb)
{
    const int idx = blockIdx.x * 256 + threadIdx.x;   // NPAD * 124
    const int row = idx / 124;
    const int k8  = (idx % 124) << 3;
    f16x8 o = {};
    if (row < NNODES) {
#pragma unroll
        for (int i = 0; i < 8; ++i) {
            const int k = k8 + i;
            o[i] = (k < DIN) ? (_Float16)(sf[(size_t)row * DIN + k] * SCALE) : (_Float16)0.f;
        }
    }
    *(f16x8*)(sfb + (size_t)row * K0PAD + k8) = o;
}

__global__ __launch_bounds__(256) void pack_w0(const float* __restrict__ Ws0,
                                               const float* __restrict__ Wn0,
                                               _Float16* __restrict__ Wp0)
{
    const int idx = blockIdx.x * 256 + threadIdx.x;   // 512 * 124
    const int nn  = idx & 511;
    const int k8  = idx >> 9;
    const float* W = (nn < 256) ? Ws0 : Wn0;
    const int n0 = nn & 255;
    f16x8 o;
#pragma unroll
    for (int i = 0; i < 8; ++i) {
        const int k = (k8 << 3) + i;
        o[i] = (k < DIN) ? (_Float16)W[(size_t)k * 256 + n0] : (_Float16)0.f;
    }
    *(f16x8*)(Wp0 + (size_t)nn * K0PAD + (k8 << 3)) = o;
}

// Ws/Wn [13][256][256] f32 -> Wpk2 [13][256(n)][512(k)] fp16: Wpk2[l][n][k] = Wcat[k][n]
__global__ __launch_bounds__(256) void pack_w2(const float* __restrict__ Ws,
                                               const float* __restrict__ Wn,
                                               _Float16* __restrict__ Wpk2)
{
    const int idx = blockIdx.x * 256 + threadIdx.x;   // 13 * 64 * 256
    const int n   = idx & 255;
    const int k8  = (idx >> 8) & 63;
    const int l   = idx >> 14;
    f16x8 o;
#pragma unroll
    for (int i = 0; i < 8; ++i) {
        const int k = (k8 << 3) + i;
        const float* W = (k < 256) ? Ws : Wn;
        o[i] = (_Float16)W[(size_t)l * 65536 + (k & 255) * 256 + n];
    }
    *(f16x8*)(Wpk2 + (size_t)l * 131072 + (size_t)n * 512 + (k8 << 3)) = o;
}

extern "C" void kernel_launch(void* const* d_in, const int* in_sizes, int n_in,
                              void* d_out, int out_size, void* d_ws, size_t ws_size,
                              hipStream_t stream)
{
    const int*   nbr = (const int*)d_in[0];
    const float* sf  = (const float*)d_in[1];
    const float* Ws0 = (const float*)d_in[2];
    const float* Wn0 = (const float*)d_in[3];
    const float* b0  = (const float*)d_in[4];
    const float* Ws  = (const float*)d_in[5];
    const float* Wn  = (const float*)d_in[6];
    const float* bb  = (const float*)d_in[7];
    const float* We  = (const float*)d_in[8];
    const float* be  = (const float*)d_in[9];
    float* out = (float*)d_out;

    // Workspace (151.6 MB):
    //   [0, 99.3MB)   : sfb [NPAD][992] fp16 -- consumed by layer-0 GEMM, then reused:
    //                     P = +0, Q = +25.6MB, Wpk2 = +51.2MB (packed AFTER layer-0 GEMM)
    //   [99.3,100.3)  : Wp0 [512][992] fp16
    //   [100.3,125.9) : ysb [NPAD][256] fp16
    //   [125.9,151.6) : ynb [NPAD][256] fp16
    uint8_t* w = (uint8_t*)d_ws;
    _Float16* sfb  = (_Float16*)w;
    _Float16* P    = (_Float16*)w;
    _Float16* Q    = P + (size_t)NPAD * 256;
    _Float16* Wpk2 = Q + (size_t)NPAD * 256;
    _Float16* Wp0  = (_Float16*)(w + (size_t)NPAD * K0PAD * 2);
    _Float16* ysb  = Wp0 + (size_t)512 * K0PAD;
    _Float16* ynb  = ysb + (size_t)NPAD * 256;

    conv_sf<<<NPAD * 124 / 256, 256, 0, stream>>>(sf, sfb);
    pack_w0<<<512 * 124 / 256, 256, 0, stream>>>(Ws0, Wn0, Wp0);

    // Layer 0 (K=992): proven round-2 config.
    gemm_dual0<<<dim3(NPAD / 128, 4), 256, 0, stream>>>(sfb, K0PAD, Wp0, ysb, ynb);
    pack_w2<<<13 * 64 * 256 / 256, 256, 0, stream>>>(Ws, Wn, Wpk2);
    combine0<<<NNODES / 4, 256, 0, stream>>>(ysb, ynb, nbr, b0, P);

    const int fg = NPAD / 64;   // 782

    for (int t = 0; t < 6; ++t) {
        const int lA = 2 * t, lB = lA + 1;
        fused_layer<0><<<fg, 256, 0, stream>>>(P, nbr, Wpk2 + (size_t)lA * 131072,
                                               bb + lA * 256, nullptr, Q, nullptr);
        fused_layer<0><<<fg, 256, 0, stream>>>(Q, nbr, Wpk2 + (size_t)lB * 131072,
                                               bb + lB * 256, P, P, nullptr);
    }

    fused_layer<1><<<fg, 256, 0, stream>>>(P, nbr, Wpk2 + (size_t)12 * 131072,
                                           bb + 12 * 256, nullptr, nullptr, out);

    coords_kernel<<<NNODES, 64, 0, stream>>>(out, We, be, out + (size_t)NNODES * 256, NNODES);
}

// Round 7
// 1587.767 us; speedup vs baseline: 1.6385x; 1.6385x over previous
//
#include <hip/hip_runtime.h>
#include <hip/hip_bf16.h>
#include <hip/hip_fp16.h>
#include <stdint.h>

#define NNODES 50000
#define NPAD   50048          // 391 * 128
#define DEG    16
#define DIN    963
#define K0PAD  992            // 31 * 32
#define DHID   256
#define SCALE  (1.0f / 1024.0f)
#define ISCALE 1024.0f

typedef __attribute__((ext_vector_type(4))) float    f32x4;
typedef __attribute__((ext_vector_type(8))) _Float16 f16x8;
typedef __attribute__((ext_vector_type(4))) _Float16 f16x4;

typedef const __attribute__((address_space(1))) void GV;
typedef __attribute__((address_space(3))) void LV;

__device__ __forceinline__ void gl2lds16(const void* g, void* l) {
    __builtin_amdgcn_global_load_lds((GV*)g, (LV*)l, 16, 0, 0);
}

// ---------------- layer-0 dual GEMM (round-2 proven, ~140us) ----------------
__global__ __launch_bounds__(256) void gemm_dual0(
    const _Float16* __restrict__ A, int K,
    const _Float16* __restrict__ Wp,
    _Float16* __restrict__ ys, _Float16* __restrict__ yn)
{
    __shared__ _Float16 lds[2][2][4096];   // [buf][A/B][kh(4)][128][8]

    const int tid  = threadIdx.x;
    const int w    = tid >> 6;
    const int lane = tid & 63;
    const int bm   = blockIdx.x * 128;
    const int nb   = blockIdx.y * 128;

    const int KT = K >> 5;

    auto stage = [&](int s, int kt) {
        const int k0 = kt << 5;
#pragma unroll
        for (int i = 0; i < 2; ++i) {
            const int j   = w + (i << 2);
            const int c   = (j << 6) + lane;
            const int row = c & 127;
            const int k8  = (c >> 7) << 3;
            gl2lds16(A  + (size_t)(bm + row) * K + k0 + k8, &lds[s][0][(size_t)j << 9]);
            gl2lds16(Wp + (size_t)(nb + row) * K + k0 + k8, &lds[s][1][(size_t)j << 9]);
        }
    };

    const int wm = (w >> 1) << 6;
    const int wn = (w & 1) << 6;
    const int lr = lane & 15;
    const int kh = lane >> 4;

    f32x4 acc[4][4] = {};

    stage(0, 0);
    __syncthreads();
    int cur = 0;
    for (int kt = 0; kt < KT; ++kt) {
        if (kt + 1 < KT) stage(cur ^ 1, kt + 1);
        f16x8 a[4], b[4];
#pragma unroll
        for (int mi = 0; mi < 4; ++mi)
            a[mi] = *(const f16x8*)&lds[cur][0][((kh << 7) + wm + (mi << 4) + lr) << 3];
#pragma unroll
        for (int ni = 0; ni < 4; ++ni)
            b[ni] = *(const f16x8*)&lds[cur][1][((kh << 7) + wn + (ni << 4) + lr) << 3];
#pragma unroll
        for (int mi = 0; mi < 4; ++mi)
#pragma unroll
            for (int ni = 0; ni < 4; ++ni)
                acc[mi][ni] = __builtin_amdgcn_mfma_f32_16x16x32_f16(a[mi], b[ni], acc[mi][ni], 0, 0, 0);
        __syncthreads();
        cur ^= 1;
    }

    _Float16* C = (blockIdx.y < 2) ? ys : yn;
    const int cb = (nb & 255) + wn;
#pragma unroll
    for (int mi = 0; mi < 4; ++mi) {
        const size_t rbase = (size_t)(bm + wm + (mi << 4) + (kh << 2)) << 8;
#pragma unroll
        for (int ni = 0; ni < 4; ++ni) {
            const int col = cb + (ni << 4) + lr;
#pragma unroll
            for (int r = 0; r < 4; ++r)
                C[rbase + ((size_t)r << 8) + col] = (_Float16)acc[mi][ni][r];
        }
    }
}

// ---------------- fused hidden layer v3: out = epi([X | gather(X)] @ Wcat + b) --------------
// R5 skeleton: 128(M) x 256(N), 512 thr = 8 waves (2M x 4N), A/B via global_load_lds,
// double-buffered [kh][row][8] LDS. v3 change: gather for step kt+1 is SPLIT --
// first 8 nbr loads issue BEFORE MFMA(kt) (latency hidden under MFMA + B-stage),
// sum tree + second 8 loads + ds_write run AFTER MFMA(kt).
template<int FINAL>
__global__ __launch_bounds__(512) void fused_layer(
    const _Float16* __restrict__ X, const int* __restrict__ nbr,
    const _Float16* __restrict__ W, const float* __restrict__ bias,
    const _Float16* __restrict__ res,
    _Float16* __restrict__ outh, float* __restrict__ outf)
{
    __shared__ _Float16 ldsA[2][4096];   // [kh(4)][128][8]  = 8KB/buf
    __shared__ _Float16 ldsB[2][8192];   // [kh(4)][256][8]  = 16KB/buf

    const int tid  = threadIdx.x;
    const int w    = tid >> 6;
    const int lane = tid & 63;
    const int bm   = blockIdx.x << 7;

    // gather role: 4 threads per row, each owns an 8-k slice of the 32-k window
    const int growg = bm + (tid >> 2);
    const int nrow  = (growg < NNODES) ? growg : (NNODES - 1);
    const int4* np  = (const int4*)(nbr + nrow * DEG);
    const int4 q0 = np[0], q1 = np[1], q2 = np[2], q3 = np[3];
    const int kq = (tid & 3) << 3;

    auto GLD = [&](int r, int ko) -> f16x8 {
        return *(const f16x8*)(X + ((size_t)r << 8) + ko);
    };
    auto stageAself = [&](int s, int kt) {
        const int c = tid;      // chunk: row=c&127, kh=c>>7
        gl2lds16(X + ((size_t)(bm + (c & 127)) << 8) + (kt << 5) + ((c >> 7) << 3),
                 &ldsA[s][(size_t)c << 3]);
    };
    auto stageB = [&](int s, int kt) {
#pragma unroll
        for (int i = 0; i < 2; ++i) {   // 1024 chunks; chunk c: n=c&255, kh=c>>8
            const int c = (i << 9) + tid;
            gl2lds16(W + ((size_t)(c & 255) << 9) + (kt << 5) + ((c >> 8) << 3),
                     &ldsB[s][(size_t)c << 3]);
        }
    };

    const int wm = (w >> 2) << 6;   // 0/64
    const int wn = (w & 3) << 6;    // 0/64/128/192
    const int lr = lane & 15;
    const int kh = lane >> 4;

    f32x4 acc[4][4] = {};
    f16x8 g0, g1, g2, g3, g4, g5, g6, g7;

    stageAself(0, 0);
    stageB(0, 0);
    __syncthreads();

    int cur = 0;
#pragma unroll
    for (int kt = 0; kt < 16; ++kt) {
        const int nxt = kt + 1;
        if (nxt < 16) {
            if (nxt < 8) {
                stageAself(cur ^ 1, nxt);
            } else {   // issue first 8 gather loads for step nxt (hidden under MFMA)
                const int ko = ((nxt - 8) << 5) + kq;
                g0 = GLD(q0.x, ko); g1 = GLD(q0.y, ko); g2 = GLD(q0.z, ko); g3 = GLD(q0.w, ko);
                g4 = GLD(q1.x, ko); g5 = GLD(q1.y, ko); g6 = GLD(q1.z, ko); g7 = GLD(q1.w, ko);
            }
            stageB(cur ^ 1, nxt);
        }
        f16x8 a[4], b[4];
#pragma unroll
        for (int mi = 0; mi < 4; ++mi)
            a[mi] = *(const f16x8*)&ldsA[cur][((kh << 7) + wm + (mi << 4) + lr) << 3];
#pragma unroll
        for (int ni = 0; ni < 4; ++ni)
            b[ni] = *(const f16x8*)&ldsB[cur][((kh << 8) + wn + (ni << 4) + lr) << 3];
#pragma unroll
        for (int mi = 0; mi < 4; ++mi)
#pragma unroll
            for (int ni = 0; ni < 4; ++ni)
                acc[mi][ni] = __builtin_amdgcn_mfma_f32_16x16x32_f16(a[mi], b[ni], acc[mi][ni], 0, 0, 0);
        if (nxt >= 8 && nxt < 16) {
            const int ko = ((nxt - 8) << 5) + kq;
            f16x8 s0 = ((g0 + g1) + (g2 + g3)) + ((g4 + g5) + (g6 + g7));
            g0 = GLD(q2.x, ko); g1 = GLD(q2.y, ko); g2 = GLD(q2.z, ko); g3 = GLD(q2.w, ko);
            g4 = GLD(q3.x, ko); g5 = GLD(q3.y, ko); g6 = GLD(q3.z, ko); g7 = GLD(q3.w, ko);
            f16x8 s1 = ((g0 + g1) + (g2 + g3)) + ((g4 + g5) + (g6 + g7));
            *(f16x8*)&ldsA[cur ^ 1][(size_t)(((tid & 3) << 7) + (tid >> 2)) << 3] = s0 + s1;
        }
        __syncthreads();
        cur ^= 1;
    }

    // epilogue. C/D: col = lane&15, row-in-tile = (lane>>4)*4 + r  [m89/m91]
    const int r0 = kh << 2;
#pragma unroll
    for (int mi = 0; mi < 4; ++mi) {
        const int grow0 = bm + wm + (mi << 4) + r0;
#pragma unroll
        for (int ni = 0; ni < 4; ++ni) {
            const int col = wn + (ni << 4) + lr;
            const float bcol = bias[col] * SCALE;
#pragma unroll
            for (int r = 0; r < 4; ++r) {
                const int grow = grow0 + r;
                float s = acc[mi][ni][r] + bcol;
                s = fmaxf(s, 0.f);
                if (res) s = ((float)res[((size_t)grow << 8) + col] + s) * 0.5f;
                if (FINAL) {
                    if (grow < NNODES) outf[((size_t)grow << 8) + col] = s * ISCALE;
                } else {
                    outh[((size_t)grow << 8) + col] = (_Float16)s;
                }
            }
        }
    }
}

// ------------- layer-0 combine: P = relu(ys + sum_j yn[nbr_j] + b0*SCALE) -------------
__global__ __launch_bounds__(256) void combine0(
    const _Float16* __restrict__ ys, const _Float16* __restrict__ yn,
    const int* __restrict__ nbr, const float* __restrict__ bias,
    _Float16* __restrict__ outh)
{
    const int w    = threadIdx.x >> 6;
    const int lane = threadIdx.x & 63;
    const int n    = (blockIdx.x << 2) + w;
    const int c4   = lane << 2;
    const size_t base = ((size_t)n << 8) + c4;

    const f16x4 ysv = *(const f16x4*)(ys + base);
    const float4 bv = *(const float4*)(bias + c4);
    float s0 = (float)ysv[0] + bv.x * SCALE;
    float s1 = (float)ysv[1] + bv.y * SCALE;
    float s2 = (float)ysv[2] + bv.z * SCALE;
    float s3 = (float)ysv[3] + bv.w * SCALE;

    const int* nr = nbr + n * DEG;
#pragma unroll
    for (int j = 0; j < DEG; ++j) {
        const f16x4 v = *(const f16x4*)(yn + (((size_t)nr[j]) << 8) + c4);
        s0 += (float)v[0]; s1 += (float)v[1]; s2 += (float)v[2]; s3 += (float)v[3];
    }
    f16x4 o;
    o[0] = (_Float16)fmaxf(s0, 0.f); o[1] = (_Float16)fmaxf(s1, 0.f);
    o[2] = (_Float16)fmaxf(s2, 0.f); o[3] = (_Float16)fmaxf(s3, 0.f);
    *(f16x4*)(outh + base) = o;
}

// ------------- coords head: out3 = x @ We (256x3) + be (fp32, unscaled) -------------
__global__ __launch_bounds__(64) void coords_kernel(
    const float* __restrict__ x, const float* __restrict__ We,
    const float* __restrict__ be, float* __restrict__ out3, int N)
{
    const int n = blockIdx.x;
    const int l = threadIdx.x;
    const float4 xv = *(const float4*)(x + (size_t)n * 256 + l * 4);
    float p0 = 0.f, p1 = 0.f, p2 = 0.f;
    const float xs[4] = {xv.x, xv.y, xv.z, xv.w};
#pragma unroll
    for (int i = 0; i < 4; ++i) {
        const int cidx = l * 4 + i;
        p0 += xs[i] * We[cidx * 3 + 0];
        p1 += xs[i] * We[cidx * 3 + 1];
        p2 += xs[i] * We[cidx * 3 + 2];
    }
#pragma unroll
    for (int off = 32; off > 0; off >>= 1) {
        p0 += __shfl_down(p0, off);
        p1 += __shfl_down(p1, off);
        p2 += __shfl_down(p2, off);
    }
    if (l == 0) {
        out3[(size_t)n * 3 + 0] = p0 + be[0];
        out3[(size_t)n * 3 + 1] = p1 + be[1];
        out3[(size_t)n * 3 + 2] = p2 + be[2];
    }
}

// ------------- conversion / packing kernels -------------
__global__ __launch_bounds__(256) void conv_sf(const float* __restrict__ sf,
                                               _Float16* __restrict__ sfb)
{
    const int idx = blockIdx.x * 256 + threadIdx.x;   // NPAD * 124
    const int row = idx / 124;
    const int k8  = (idx % 124) << 3;
    f16x8 o = {};
    if (row < NNODES) {
#pragma unroll
        for (int i = 0; i < 8; ++i) {
            const int k = k8 + i;
            o[i] = (k < DIN) ? (_Float16)(sf[(size_t)row * DIN + k] * SCALE) : (_Float16)0.f;
        }
    }
    *(f16x8*)(sfb + (size_t)row * K0PAD + k8) = o;
}

__global__ __launch_bounds__(256) void pack_w0(const float* __restrict__ Ws0,
                                               const float* __restrict__ Wn0,
                                               _Float16* __restrict__ Wp0)
{
    const int idx = blockIdx.x * 256 + threadIdx.x;   // 512 * 124
    const int nn  = idx & 511;
    const int k8  = idx >> 9;
    const float* W = (nn < 256) ? Ws0 : Wn0;
    const int n0 = nn & 255;
    f16x8 o;
#pragma unroll
    for (int i = 0; i < 8; ++i) {
        const int k = (k8 << 3) + i;
        o[i] = (k < DIN) ? (_Float16)W[(size_t)k * 256 + n0] : (_Float16)0.f;
    }
    *(f16x8*)(Wp0 + (size_t)nn * K0PAD + (k8 << 3)) = o;
}

// Ws/Wn [13][256][256] f32 -> Wpk2 [13][256(n)][512(k)] fp16: Wpk2[l][n][k] = Wcat[k][n]
__global__ __launch_bounds__(256) void pack_w2(const float* __restrict__ Ws,
                                               const float* __restrict__ Wn,
                                               _Float16* __restrict__ Wpk2)
{
    const int idx = blockIdx.x * 256 + threadIdx.x;   // 13 * 64 * 256
    const int n   = idx & 255;
    const int k8  = (idx >> 8) & 63;
    const int l   = idx >> 14;
    f16x8 o;
#pragma unroll
    for (int i = 0; i < 8; ++i) {
        const int k = (k8 << 3) + i;
        const float* W = (k < 256) ? Ws : Wn;
        o[i] = (_Float16)W[(size_t)l * 65536 + (k & 255) * 256 + n];
    }
    *(f16x8*)(Wpk2 + (size_t)l * 131072 + (size_t)n * 512 + (k8 << 3)) = o;
}

extern "C" void kernel_launch(void* const* d_in, const int* in_sizes, int n_in,
                              void* d_out, int out_size, void* d_ws, size_t ws_size,
                              hipStream_t stream)
{
    const int*   nbr = (const int*)d_in[0];
    const float* sf  = (const float*)d_in[1];
    const float* Ws0 = (const float*)d_in[2];
    const float* Wn0 = (const float*)d_in[3];
    const float* b0  = (const float*)d_in[4];
    const float* Ws  = (const float*)d_in[5];
    const float* Wn  = (const float*)d_in[6];
    const float* bb  = (const float*)d_in[7];
    const float* We  = (const float*)d_in[8];
    const float* be  = (const float*)d_in[9];
    float* out = (float*)d_out;

    // Workspace (151.6 MB):
    //   [0, 99.3MB)   : sfb [NPAD][992] fp16 -- consumed by layer-0 GEMM, then reused:
    //                     P = +0, Q = +25.6MB, Wpk2 = +51.2MB (packed AFTER layer-0 GEMM)
    //   [99.3,100.3)  : Wp0 [512][992] fp16
    //   [100.3,125.9) : ysb [NPAD][256] fp16
    //   [125.9,151.6) : ynb [NPAD][256] fp16
    uint8_t* w = (uint8_t*)d_ws;
    _Float16* sfb  = (_Float16*)w;
    _Float16* P    = (_Float16*)w;
    _Float16* Q    = P + (size_t)NPAD * 256;
    _Float16* Wpk2 = Q + (size_t)NPAD * 256;
    _Float16* Wp0  = (_Float16*)(w + (size_t)NPAD * K0PAD * 2);
    _Float16* ysb  = Wp0 + (size_t)512 * K0PAD;
    _Float16* ynb  = ysb + (size_t)NPAD * 256;

    conv_sf<<<NPAD * 124 / 256, 256, 0, stream>>>(sf, sfb);
    pack_w0<<<512 * 124 / 256, 256, 0, stream>>>(Ws0, Wn0, Wp0);

    // Layer 0 (K=992): proven round-2 config.
    gemm_dual0<<<dim3(NPAD / 128, 4), 256, 0, stream>>>(sfb, K0PAD, Wp0, ysb, ynb);
    pack_w2<<<13 * 64 * 256 / 256, 256, 0, stream>>>(Ws, Wn, Wpk2);
    combine0<<<NNODES / 4, 256, 0, stream>>>(ysb, ynb, nbr, b0, P);

    const int fg = NPAD / 128;   // 391

    for (int t = 0; t < 6; ++t) {
        const int lA = 2 * t, lB = lA + 1;
        fused_layer<0><<<fg, 512, 0, stream>>>(P, nbr, Wpk2 + (size_t)lA * 131072,
                                               bb + lA * 256, nullptr, Q, nullptr);
        fused_layer<0><<<fg, 512, 0, stream>>>(Q, nbr, Wpk2 + (size_t)lB * 131072,
                                               bb + lB * 256, P, P, nullptr);
    }

    fused_layer<1><<<fg, 512, 0, stream>>>(P, nbr, Wpk2 + (size_t)12 * 131072,
                                           bb + 12 * 256, nullptr, nullptr, out);

    coords_kernel<<<NNODES, 64, 0, stream>>>(out, We, be, out + (size_t)NNODES * 256, NNODES);
}